// Round 1
// baseline (151.158 us; speedup 1.0000x reference)
//
#include <hip/hip_runtime.h>
#include <hip/hip_bf16.h>

typedef __hip_bfloat16 bf16;
typedef unsigned int u32;

#define NPAIR 8192   // B*NCG

// ws float layout
#define WS_S1   0      // support1 [2][6][128]
#define WS_AT1  1536   // attn table layer1 [7][128] (row 0 zeroed)
#define WS_AT2  2432   // attn table layer2 [7][128]
#define WS_S2I  3328   // support2 for init nodes [2][2][128]
#define WS_FLAG 3840   // 1.0 if inputs are bf16, 0.0 if fp32

__device__ __forceinline__ float ldf(const void* p, int i, bool isbf) {
  return isbf ? __bfloat162float(((const bf16*)p)[i]) : ((const float*)p)[i];
}

__device__ __forceinline__ float sigmoidf_(float x) {
  return 1.0f / (1.0f + __expf(-x));
}

// ---------------- Phase A: batch-independent tables (1 block) ----------------
__global__ __launch_bounds__(512) void precompute_kernel(
    const void* __restrict__ init_emb, const void* __restrict__ other_emb,
    const void* __restrict__ op_embs,  const void* __restrict__ Wx,
    const void* __restrict__ bx,       const void* __restrict__ W1,
    const void* __restrict__ Wa1,      const void* __restrict__ ba1,
    const void* __restrict__ W2,       const void* __restrict__ Wa2,
    const void* __restrict__ ba2,      float* __restrict__ ws)
{
  const int t = threadIdx.x;

  // --- dtype detection: interpret Wx words' low 16 bits as bf16 ---
  float mx = 0.f;
  for (int i = t; i < 48 * 48 / 2; i += 512) {
    u32 w = ((const u32*)Wx)[i];
    mx = fmaxf(mx, fabsf(__uint_as_float(w << 16)));
  }
  #pragma unroll
  for (int d = 32; d > 0; d >>= 1) mx = fmaxf(mx, __shfl_down(mx, d));
  __shared__ float wmax[8];
  if ((t & 63) == 0) wmax[t >> 6] = mx;
  __syncthreads();
  float m = 0.f;
  #pragma unroll
  for (int i = 0; i < 8; ++i) m = fmaxf(m, wmax[i]);
  const bool isbf = (m < 4.0f);   // genuine bf16 Wx values are <= ~0.15
  if (t == 0) ws[WS_FLAG] = isbf ? 1.f : 0.f;

  __shared__ float y0[2 * 6 * 48];     // node @ Wx + bx
  __shared__ float s1sh[2 * 6 * 128];  // support1

  // stage 1: y0[c][i][h]
  for (int idx = t; idx < 2 * 6 * 48; idx += 512) {
    int c = idx / 288, i = (idx / 48) % 6, h = idx % 48;
    float acc = ldf(bx, h, isbf);
    const int nbase = (i < 2) ? ((c * 2 + i) * 48) : (c * 48);
    const void* nptr = (i < 2) ? init_emb : other_emb;
    for (int d = 0; d < 48; ++d)
      acc += ldf(nptr, nbase + d, isbf) * ldf(Wx, d * 48 + h, isbf);
    y0[idx] = acc;
  }
  __syncthreads();

  // stage 2: support1[c][i][o] = y0 @ W1
  for (int idx = t; idx < 2 * 6 * 128; idx += 512) {
    int c = idx / 768, i = (idx >> 7) % 6, o = idx & 127;
    const float* yp = y0 + (c * 6 + i) * 48;
    float acc = 0.f;
    for (int h = 0; h < 48; ++h) acc += yp[h] * ldf(W1, h * 128 + o, isbf);
    s1sh[idx] = acc;
    ws[WS_S1 + idx] = acc;
  }

  // stage 3: attn tables (independent of stages 1/2)
  for (int idx = t; idx < 7 * 128; idx += 512) {
    int op = idx >> 7, o = idx & 127;
    float a1 = ldf(ba1, o, isbf), a2 = ldf(ba2, o, isbf);
    for (int d = 0; d < 48; ++d) {
      float e = ldf(op_embs, op * 48 + d, isbf);
      a1 += e * ldf(Wa1, d * 128 + o, isbf);
      a2 += e * ldf(Wa2, d * 128 + o, isbf);
    }
    ws[WS_AT1 + idx] = (op == 0) ? 0.f : sigmoidf_(a1);  // mask baked in
    ws[WS_AT2 + idx] = (op == 0) ? 0.f : sigmoidf_(a2);
  }
  __syncthreads();

  // stage 4: support2 for init nodes (no incoming edges -> y1 = relu(support1))
  for (int idx = t; idx < 2 * 2 * 128; idx += 512) {
    int c = idx >> 8, i = (idx >> 7) & 1, o = idx & 127;
    const float* sp = s1sh + (c * 6 + i) * 128;
    float acc = 0.f;
    for (int h = 0; h < 128; ++h)
      acc += fmaxf(sp[h], 0.f) * ldf(W2, h * 128 + o, isbf);
    ws[WS_S2I + idx] = acc;
  }
}

// ---------------- Phase B: per-(b,c) fused layer1 + matmul + layer2 ----------
#define COMP4(v, j) ((j) == 0 ? (v).x : (j) == 1 ? (v).y : (j) == 2 ? (v).z : (v).w)

template <bool ISBF>
__device__ __forceinline__ void gemm_tail(
    const void* __restrict__ W2, const float* __restrict__ ws,
    void* __restrict__ out, const float* __restrict__ y1p,
    const int* f, const int* op, int P, int c, int o2)
{
  float ax0 = 0, ax1 = 0, ax2 = 0, ax3 = 0;
  float ay0 = 0, ay1 = 0, ay2 = 0, ay3 = 0;

  for (int h = 0; h < 128; h += 4) {
    // wave-broadcast LDS reads (all 64 lanes same address: conflict-free)
    float4 q0 = *(const float4*)(y1p + 0 * 128 + h);
    float4 q1 = *(const float4*)(y1p + 1 * 128 + h);
    float4 q2 = *(const float4*)(y1p + 2 * 128 + h);
    float4 q3 = *(const float4*)(y1p + 3 * 128 + h);
    #pragma unroll
    for (int j = 0; j < 4; ++j) {
      float w0, w1;
      if (ISBF) {
        u32 w = ((const u32*)W2)[(h + j) * 64 + o2];  // 2 bf16 channels
        w0 = __uint_as_float(w << 16);                 // bf16 -> f32 = shl 16
        w1 = __uint_as_float(w & 0xffff0000u);
      } else {
        float2 wf = ((const float2*)W2)[(h + j) * 64 + o2];
        w0 = wf.x; w1 = wf.y;
      }
      float y;
      y = COMP4(q0, j); ax0 += y * w0; ay0 += y * w1;
      y = COMP4(q1, j); ax1 += y * w0; ay1 += y * w1;
      y = COMP4(q2, j); ax2 += y * w0; ay2 += y * w1;
      y = COMP4(q3, j); ax3 += y * w0; ay3 += y * w1;
    }
  }

  // layer-2 edge aggregation + mean over nodes 2..5
  const float2* at2 = (const float2*)(ws + WS_AT2);
  const float2* s2i = (const float2*)(ws + WS_S2I) + c * 128;
  float r0 = ax0 + ax1 + ax2 + ax3;
  float r1 = ay0 + ay1 + ay2 + ay3;
  #pragma unroll
  for (int e = 0; e < 8; ++e) {
    int fe = f[e];
    float2 a = at2[op[e] * 64 + o2];  // row 0 is zero -> masks op==NONE
    float sx, sy;
    if (fe == 0)      { float2 s = s2i[o2];      sx = s.x; sy = s.y; }
    else if (fe == 1) { float2 s = s2i[64 + o2]; sx = s.x; sy = s.y; }
    else if (fe == 2) { sx = ax0; sy = ay0; }
    else if (fe == 3) { sx = ax1; sy = ay1; }
    else if (fe == 4) { sx = ax2; sy = ay2; }
    else              { sx = ax3; sy = ay3; }
    r0 += a.x * sx;
    r1 += a.y * sy;
  }
  r0 *= 0.25f; r1 *= 0.25f;

  if (ISBF) {
    __hip_bfloat162 v;
    v.x = __float2bfloat16(r0);
    v.y = __float2bfloat16(r1);
    ((__hip_bfloat162*)out)[P * 64 + o2] = v;
  } else {
    ((float2*)out)[P * 64 + o2] = make_float2(r0, r1);
  }
}

__global__ __launch_bounds__(256) void main_kernel(
    const int* __restrict__ archs, const void* __restrict__ W2,
    const float* __restrict__ ws, void* __restrict__ out)
{
  const int t  = threadIdx.x;
  const int pp = t >> 6;          // pair slot in block (== wave id)
  const int o2 = t & 63;          // channel pair: channels 2*o2, 2*o2+1
  const int P  = blockIdx.x * 4 + pp;   // global (b,c) pair
  const int c  = P & 1;

  __shared__ float y1sh[4][512];  // [pair][node 2..5][128]
  __shared__ int   archsh[64];
  if (t < 64) archsh[t] = archs[blockIdx.x * 64 + t];
  __syncthreads();

  int f[8], op[8];
  #pragma unroll
  for (int e = 0; e < 8; ++e) { f[e] = archsh[pp * 16 + e]; op[e] = archsh[pp * 16 + 8 + e]; }

  const float2* s1p = (const float2*)ws + c * 384;      // support1[c] as [6][64] float2
  const float2* at1 = (const float2*)(ws + WS_AT1);     // [7][64] float2

  // layer 1 for nodes 2..5 (attn row 0 is zero -> branchless mask)
  #pragma unroll
  for (int i = 0; i < 4; ++i) {
    float2 v = s1p[(2 + i) * 64 + o2];
    int e0 = 2 * i, e1 = 2 * i + 1;
    float2 A0 = at1[op[e0] * 64 + o2];
    float2 B0 = s1p[f[e0] * 64 + o2];
    float2 A1 = at1[op[e1] * 64 + o2];
    float2 B1 = s1p[f[e1] * 64 + o2];
    v.x += A0.x * B0.x + A1.x * B1.x;
    v.y += A0.y * B0.y + A1.y * B1.y;
    ((float2*)(y1sh[pp] + i * 128))[o2] =
        make_float2(fmaxf(v.x, 0.f), fmaxf(v.y, 0.f));
  }
  __syncthreads();

  const bool isbf = (ws[WS_FLAG] != 0.f);
  if (isbf) gemm_tail<true >(W2, ws, out, y1sh[pp], f, op, P, c, o2);
  else      gemm_tail<false>(W2, ws, out, y1sh[pp], f, op, P, c, o2);
}

extern "C" void kernel_launch(void* const* d_in, const int* in_sizes, int n_in,
                              void* d_out, int out_size, void* d_ws, size_t ws_size,
                              hipStream_t stream) {
  const int* archs = (const int*)d_in[0];
  float* ws = (float*)d_ws;
  precompute_kernel<<<1, 512, 0, stream>>>(
      d_in[1], d_in[2], d_in[3], d_in[4], d_in[5], d_in[6],
      d_in[7], d_in[8], d_in[9], d_in[10], d_in[11], ws);
  main_kernel<<<NPAIR / 4, 256, 0, stream>>>(archs, d_in[9], ws, d_out);
}

// Round 5
// 147.966 us; speedup vs baseline: 1.0216x; 1.0216x over previous
//
#include <hip/hip_runtime.h>
#include <hip/hip_bf16.h>

typedef __hip_bfloat16 bf16;
typedef unsigned int u32;

#define NPAIR 8192   // B*NCG

// ws float layout
#define WS_S1   0      // support1 [2][6][128]
#define WS_AT1  1536   // attn table layer1 [7][128] (row 0 zeroed)
#define WS_AT2  2432   // attn table layer2 [7][128]
#define WS_S2I  3328   // support2 for init nodes [2][2][128]
#define WS_FLAG 3840   // 1.0 if inputs are bf16, 0.0 if fp32

__device__ __forceinline__ float ldf(const void* p, int i, bool isbf) {
  return isbf ? __bfloat162float(((const bf16*)p)[i]) : ((const float*)p)[i];
}

__device__ __forceinline__ float sigmoidf_(float x) {
  return 1.0f / (1.0f + __expf(-x));
}

// ---------------- Phase A: batch-independent tables ----------------
// EXACT round-1 body (the known-pass). Only diff: 8 blocks; stages 3 and 4
// sliced per block via LOOP BOUNDS (no if-guards, no pragmas, no load rewrite);
// stages 1-2 computed redundantly by every block with unconditional stores
// (identical values from identical inputs -> benign duplicate writes).
__global__ __launch_bounds__(512) void precompute_kernel(
    const void* __restrict__ init_emb, const void* __restrict__ other_emb,
    const void* __restrict__ op_embs,  const void* __restrict__ Wx,
    const void* __restrict__ bx,       const void* __restrict__ W1,
    const void* __restrict__ Wa1,      const void* __restrict__ ba1,
    const void* __restrict__ W2,       const void* __restrict__ Wa2,
    const void* __restrict__ ba2,      float* __restrict__ ws)
{
  const int t   = threadIdx.x;
  const int blk = blockIdx.x;   // 0..7

  // --- dtype detection: interpret Wx words' low 16 bits as bf16 ---
  float mx = 0.f;
  for (int i = t; i < 48 * 48 / 2; i += 512) {
    u32 w = ((const u32*)Wx)[i];
    mx = fmaxf(mx, fabsf(__uint_as_float(w << 16)));
  }
  #pragma unroll
  for (int d = 32; d > 0; d >>= 1) mx = fmaxf(mx, __shfl_down(mx, d));
  __shared__ float wmax[8];
  if ((t & 63) == 0) wmax[t >> 6] = mx;
  __syncthreads();
  float m = 0.f;
  #pragma unroll
  for (int i = 0; i < 8; ++i) m = fmaxf(m, wmax[i]);
  const bool isbf = (m < 4.0f);   // genuine bf16 Wx values are <= ~0.15
  if (t == 0) ws[WS_FLAG] = isbf ? 1.f : 0.f;

  __shared__ float y0[2 * 6 * 48];     // node @ Wx + bx
  __shared__ float s1sh[2 * 6 * 128];  // support1

  // stage 1: y0[c][i][h]
  for (int idx = t; idx < 2 * 6 * 48; idx += 512) {
    int c = idx / 288, i = (idx / 48) % 6, h = idx % 48;
    float acc = ldf(bx, h, isbf);
    const int nbase = (i < 2) ? ((c * 2 + i) * 48) : (c * 48);
    const void* nptr = (i < 2) ? init_emb : other_emb;
    for (int d = 0; d < 48; ++d)
      acc += ldf(nptr, nbase + d, isbf) * ldf(Wx, d * 48 + h, isbf);
    y0[idx] = acc;
  }
  __syncthreads();

  // stage 2: support1[c][i][o] = y0 @ W1 (all blocks, duplicate same-value ws writes)
  for (int idx = t; idx < 2 * 6 * 128; idx += 512) {
    int c = idx / 768, i = (idx >> 7) % 6, o = idx & 127;
    const float* yp = y0 + (c * 6 + i) * 48;
    float acc = 0.f;
    for (int h = 0; h < 48; ++h) acc += yp[h] * ldf(W1, h * 128 + o, isbf);
    s1sh[idx] = acc;
    ws[WS_S1 + idx] = acc;
  }

  // stage 3: attn tables — sliced: this block covers [blk*112, (blk+1)*112)
  for (int idx = blk * 112 + t; idx < (blk + 1) * 112; idx += 512) {
    int op = idx >> 7, o = idx & 127;
    float a1 = ldf(ba1, o, isbf), a2 = ldf(ba2, o, isbf);
    for (int d = 0; d < 48; ++d) {
      float e = ldf(op_embs, op * 48 + d, isbf);
      a1 += e * ldf(Wa1, d * 128 + o, isbf);
      a2 += e * ldf(Wa2, d * 128 + o, isbf);
    }
    ws[WS_AT1 + idx] = (op == 0) ? 0.f : sigmoidf_(a1);  // mask baked in
    ws[WS_AT2 + idx] = (op == 0) ? 0.f : sigmoidf_(a2);
  }
  __syncthreads();

  // stage 4: support2 for init nodes — sliced: [blk*64, (blk+1)*64)
  for (int idx = blk * 64 + t; idx < (blk + 1) * 64; idx += 512) {
    int c = idx >> 8, i = (idx >> 7) & 1, o = idx & 127;
    const float* sp = s1sh + (c * 6 + i) * 128;
    float acc = 0.f;
    for (int h = 0; h < 128; ++h)
      acc += fmaxf(sp[h], 0.f) * ldf(W2, h * 128 + o, isbf);
    ws[WS_S2I + idx] = acc;
  }
}

// ---------------- Phase B: VERBATIM round-1 main (known-passing) ------------
#define COMP4(v, j) ((j) == 0 ? (v).x : (j) == 1 ? (v).y : (j) == 2 ? (v).z : (v).w)

template <bool ISBF>
__device__ __forceinline__ void gemm_tail(
    const void* __restrict__ W2, const float* __restrict__ ws,
    void* __restrict__ out, const float* __restrict__ y1p,
    const int* f, const int* op, int P, int c, int o2)
{
  float ax0 = 0, ax1 = 0, ax2 = 0, ax3 = 0;
  float ay0 = 0, ay1 = 0, ay2 = 0, ay3 = 0;

  for (int h = 0; h < 128; h += 4) {
    // wave-broadcast LDS reads (all 64 lanes same address: conflict-free)
    float4 q0 = *(const float4*)(y1p + 0 * 128 + h);
    float4 q1 = *(const float4*)(y1p + 1 * 128 + h);
    float4 q2 = *(const float4*)(y1p + 2 * 128 + h);
    float4 q3 = *(const float4*)(y1p + 3 * 128 + h);
    #pragma unroll
    for (int j = 0; j < 4; ++j) {
      float w0, w1;
      if (ISBF) {
        u32 w = ((const u32*)W2)[(h + j) * 64 + o2];  // 2 bf16 channels
        w0 = __uint_as_float(w << 16);                 // bf16 -> f32 = shl 16
        w1 = __uint_as_float(w & 0xffff0000u);
      } else {
        float2 wf = ((const float2*)W2)[(h + j) * 64 + o2];
        w0 = wf.x; w1 = wf.y;
      }
      float y;
      y = COMP4(q0, j); ax0 += y * w0; ay0 += y * w1;
      y = COMP4(q1, j); ax1 += y * w0; ay1 += y * w1;
      y = COMP4(q2, j); ax2 += y * w0; ay2 += y * w1;
      y = COMP4(q3, j); ax3 += y * w0; ay3 += y * w1;
    }
  }

  // layer-2 edge aggregation + mean over nodes 2..5
  const float2* at2 = (const float2*)(ws + WS_AT2);
  const float2* s2i = (const float2*)(ws + WS_S2I) + c * 128;
  float r0 = ax0 + ax1 + ax2 + ax3;
  float r1 = ay0 + ay1 + ay2 + ay3;
  #pragma unroll
  for (int e = 0; e < 8; ++e) {
    int fe = f[e];
    float2 a = at2[op[e] * 64 + o2];  // row 0 is zero -> masks op==NONE
    float sx, sy;
    if (fe == 0)      { float2 s = s2i[o2];      sx = s.x; sy = s.y; }
    else if (fe == 1) { float2 s = s2i[64 + o2]; sx = s.x; sy = s.y; }
    else if (fe == 2) { sx = ax0; sy = ay0; }
    else if (fe == 3) { sx = ax1; sy = ay1; }
    else if (fe == 4) { sx = ax2; sy = ay2; }
    else              { sx = ax3; sy = ay3; }
    r0 += a.x * sx;
    r1 += a.y * sy;
  }
  r0 *= 0.25f; r1 *= 0.25f;

  if (ISBF) {
    __hip_bfloat162 v;
    v.x = __float2bfloat16(r0);
    v.y = __float2bfloat16(r1);
    ((__hip_bfloat162*)out)[P * 64 + o2] = v;
  } else {
    ((float2*)out)[P * 64 + o2] = make_float2(r0, r1);
  }
}

__global__ __launch_bounds__(256) void main_kernel(
    const int* __restrict__ archs, const void* __restrict__ W2,
    const float* __restrict__ ws, void* __restrict__ out)
{
  const int t  = threadIdx.x;
  const int pp = t >> 6;          // pair slot in block (== wave id)
  const int o2 = t & 63;          // channel pair: channels 2*o2, 2*o2+1
  const int P  = blockIdx.x * 4 + pp;   // global (b,c) pair
  const int c  = P & 1;

  __shared__ float y1sh[4][512];  // [pair][node 2..5][128]
  __shared__ int   archsh[64];
  if (t < 64) archsh[t] = archs[blockIdx.x * 64 + t];
  __syncthreads();

  int f[8], op[8];
  #pragma unroll
  for (int e = 0; e < 8; ++e) { f[e] = archsh[pp * 16 + e]; op[e] = archsh[pp * 16 + 8 + e]; }

  const float2* s1p = (const float2*)ws + c * 384;      // support1[c] as [6][64] float2
  const float2* at1 = (const float2*)(ws + WS_AT1);     // [7][64] float2

  // layer 1 for nodes 2..5 (attn row 0 is zero -> branchless mask)
  #pragma unroll
  for (int i = 0; i < 4; ++i) {
    float2 v = s1p[(2 + i) * 64 + o2];
    int e0 = 2 * i, e1 = 2 * i + 1;
    float2 A0 = at1[op[e0] * 64 + o2];
    float2 B0 = s1p[f[e0] * 64 + o2];
    float2 A1 = at1[op[e1] * 64 + o2];
    float2 B1 = s1p[f[e1] * 64 + o2];
    v.x += A0.x * B0.x + A1.x * B1.x;
    v.y += A0.y * B0.y + A1.y * B1.y;
    ((float2*)(y1sh[pp] + i * 128))[o2] =
        make_float2(fmaxf(v.x, 0.f), fmaxf(v.y, 0.f));
  }
  __syncthreads();

  const bool isbf = (ws[WS_FLAG] != 0.f);
  if (isbf) gemm_tail<true >(W2, ws, out, y1sh[pp], f, op, P, c, o2);
  else      gemm_tail<false>(W2, ws, out, y1sh[pp], f, op, P, c, o2);
}

extern "C" void kernel_launch(void* const* d_in, const int* in_sizes, int n_in,
                              void* d_out, int out_size, void* d_ws, size_t ws_size,
                              hipStream_t stream) {
  const int* archs = (const int*)d_in[0];
  float* ws = (float*)d_ws;
  precompute_kernel<<<8, 512, 0, stream>>>(
      d_in[1], d_in[2], d_in[3], d_in[4], d_in[5], d_in[6],
      d_in[7], d_in[8], d_in[9], d_in[10], d_in[11], ws);
  main_kernel<<<NPAIR / 4, 256, 0, stream>>>(archs, d_in[9], ws, d_out);
}

// Round 6
// 134.018 us; speedup vs baseline: 1.1279x; 1.1041x over previous
//
#include <hip/hip_runtime.h>

typedef unsigned int u32;

#define NPAIR 8192   // B*NCG

// ws float layout (all fp32 — inputs/outputs are float32 per the reference;
// R2/R3/R4 NaNs were fp32-bits-reinterpreted-as-bf16 (NaN-pattern bf16s).
// R1/R5's runtime detection picked the fp32 path; WRITE_SIZE=4MB confirms
// fp32 output.)
#define WS_S1   0      // support1 [2][6][128]
#define WS_AT1  1536   // attn table layer1 [7][128] (row 0 zeroed = NONE mask)
#define WS_AT2  2432   // attn table layer2 [7][128]
#define WS_S2I  3328   // support2 for init nodes [2][2][128]

__device__ __forceinline__ float sigmoidf_(float x) {
  return 1.0f / (1.0f + __expf(-x));
}

// ---------------- Phase A: batch-independent tables ----------------
// R5-validated structure (strided loops, loop-bound slicing across 8 blocks,
// no if-guards, no unroll-N pragmas). Only change vs R5: plain fp32 loads
// (the per-element isbf select was blocking load pipelining -> 62us).
__global__ __launch_bounds__(512) void precompute_kernel(
    const float* __restrict__ init_emb, const float* __restrict__ other_emb,
    const float* __restrict__ op_embs,  const float* __restrict__ Wx,
    const float* __restrict__ bx,       const float* __restrict__ W1,
    const float* __restrict__ Wa1,      const float* __restrict__ ba1,
    const float* __restrict__ W2,       const float* __restrict__ Wa2,
    const float* __restrict__ ba2,      float* __restrict__ ws)
{
  const int t   = threadIdx.x;
  const int blk = blockIdx.x;   // 0..7

  __shared__ float y0[2 * 6 * 48];     // node @ Wx + bx
  __shared__ float s1sh[2 * 6 * 128];  // support1

  // stage 1: y0[c][i][h] = node @ Wx + bx
  for (int idx = t; idx < 2 * 6 * 48; idx += 512) {
    int c = idx / 288, i = (idx / 48) % 6, h = idx % 48;
    const float* nptr = (i < 2) ? (init_emb + (c * 2 + i) * 48)
                                : (other_emb + c * 48);
    float acc = bx[h];
    for (int d = 0; d < 48; ++d)
      acc += nptr[d] * Wx[d * 48 + h];
    y0[idx] = acc;
  }
  __syncthreads();

  // stage 2: support1[c][i][o] = y0 @ W1 (all blocks; duplicate same-value ws
  // writes are benign)
  for (int idx = t; idx < 2 * 6 * 128; idx += 512) {
    int ci = idx >> 7, o = idx & 127;
    const float* yp = y0 + ci * 48;
    float acc = 0.f;
    for (int h = 0; h < 48; ++h) acc += yp[h] * W1[h * 128 + o];
    s1sh[idx] = acc;
    ws[WS_S1 + idx] = acc;
  }

  // stage 3: attn tables — sliced via loop bounds: [blk*112, (blk+1)*112)
  for (int idx = blk * 112 + t; idx < (blk + 1) * 112; idx += 512) {
    int op = idx >> 7, o = idx & 127;
    float a1 = ba1[o], a2 = ba2[o];
    for (int d = 0; d < 48; ++d) {
      float e = op_embs[op * 48 + d];
      a1 += e * Wa1[d * 128 + o];
      a2 += e * Wa2[d * 128 + o];
    }
    ws[WS_AT1 + idx] = (op == 0) ? 0.f : sigmoidf_(a1);  // NONE mask baked in
    ws[WS_AT2 + idx] = (op == 0) ? 0.f : sigmoidf_(a2);
  }
  __syncthreads();

  // stage 4: support2 for init nodes (no in-edges -> y1 = relu(support1)),
  // sliced: [blk*64, (blk+1)*64)
  for (int idx = blk * 64 + t; idx < (blk + 1) * 64; idx += 512) {
    int c = idx >> 8, i = (idx >> 7) & 1, o = idx & 127;
    const float* sp = s1sh + (c * 6 + i) * 128;
    float acc = 0.f;
    for (int h = 0; h < 128; ++h)
      acc += fmaxf(sp[h], 0.f) * W2[h * 128 + o];
    ws[WS_S2I + idx] = acc;
  }
}

// ---------------- Phase B: per-(b,c) fused layer1 + matmul + layer2 ----------
// R5's executed (fp32) path verbatim; structural changes only: 512-thread
// blocks (8 pairs/block, 8 waves), grid 1024 = exactly 4 blocks/CU -> 32
// waves/CU for latency hiding (R5: VALUBusy 23%, latency-bound at ~10
// waves/CU). launch_bounds(512,8) caps VGPR at 64 (R5 used 56).
#define COMP4(v, j) ((j) == 0 ? (v).x : (j) == 1 ? (v).y : (j) == 2 ? (v).z : (v).w)

__global__ __launch_bounds__(512, 8) void main_kernel(
    const int* __restrict__ archs, const float* __restrict__ W2,
    const float* __restrict__ ws, float* __restrict__ out)
{
  const int t  = threadIdx.x;
  const int w  = t >> 6;          // wave id == pair slot in block (0..7)
  const int o2 = t & 63;          // channel pair: channels 2*o2, 2*o2+1
  const int P  = blockIdx.x * 8 + w;    // global (b,c) pair
  const int c  = P & 1;

  __shared__ float y1sh[8][512];  // [pair][node 2..5][128]
  __shared__ int   archsh[128];
  if (t < 128) archsh[t] = archs[blockIdx.x * 128 + t];
  __syncthreads();

  int f[8], op[8];
  #pragma unroll
  for (int e = 0; e < 8; ++e) { f[e] = archsh[w * 16 + e]; op[e] = archsh[w * 16 + 8 + e]; }

  const float2* s1p = (const float2*)ws + c * 384;      // support1[c] as [6][64] float2
  const float2* at1 = (const float2*)(ws + WS_AT1);     // [7][64] float2
  const float2* at2 = (const float2*)(ws + WS_AT2);
  const float2* s2i = (const float2*)(ws + WS_S2I) + c * 128;

  // pre-issue epilogue table loads (latency hidden behind the gemm below)
  float2 A2[8];
  #pragma unroll
  for (int e = 0; e < 8; ++e) A2[e] = at2[op[e] * 64 + o2];
  float2 S0 = s2i[o2], S1 = s2i[64 + o2];

  // layer 1 for nodes 2..5 (attn table row 0 is zero -> branchless mask)
  #pragma unroll
  for (int i = 0; i < 4; ++i) {
    float2 v = s1p[(2 + i) * 64 + o2];
    int e0 = 2 * i, e1 = 2 * i + 1;
    float2 A0 = at1[op[e0] * 64 + o2];
    float2 B0 = s1p[f[e0] * 64 + o2];
    float2 A1 = at1[op[e1] * 64 + o2];
    float2 B1 = s1p[f[e1] * 64 + o2];
    v.x += A0.x * B0.x + A1.x * B1.x;
    v.y += A0.y * B0.y + A1.y * B1.y;
    ((float2*)(y1sh[w] + i * 128))[o2] =
        make_float2(fmaxf(v.x, 0.f), fmaxf(v.y, 0.f));
  }
  __syncthreads();

  // gemm: support2[node 2..5][2 channels] per lane; W2 fp32 float2 via L1/L2
  const float* y1p = y1sh[w];
  const float2* W2f = (const float2*)W2;
  float ax0 = 0, ax1 = 0, ax2 = 0, ax3 = 0;
  float ay0 = 0, ay1 = 0, ay2 = 0, ay3 = 0;

  for (int h = 0; h < 128; h += 4) {
    float4 q0 = *(const float4*)(y1p + 0 * 128 + h);  // wave-broadcast LDS
    float4 q1 = *(const float4*)(y1p + 1 * 128 + h);
    float4 q2 = *(const float4*)(y1p + 2 * 128 + h);
    float4 q3 = *(const float4*)(y1p + 3 * 128 + h);
    #pragma unroll
    for (int j = 0; j < 4; ++j) {
      float2 wf = W2f[(h + j) * 64 + o2];
      float w0 = wf.x, w1 = wf.y;
      float y;
      y = COMP4(q0, j); ax0 += y * w0; ay0 += y * w1;
      y = COMP4(q1, j); ax1 += y * w0; ay1 += y * w1;
      y = COMP4(q2, j); ax2 += y * w0; ay2 += y * w1;
      y = COMP4(q3, j); ax3 += y * w0; ay3 += y * w1;
    }
  }

  // layer-2 edge aggregation + mean over nodes 2..5
  float r0 = ax0 + ax1 + ax2 + ax3;
  float r1 = ay0 + ay1 + ay2 + ay3;
  #pragma unroll
  for (int e = 0; e < 8; ++e) {
    int fe = f[e];
    float sx, sy;
    if (fe == 0)      { sx = S0.x; sy = S0.y; }
    else if (fe == 1) { sx = S1.x; sy = S1.y; }
    else if (fe == 2) { sx = ax0; sy = ay0; }
    else if (fe == 3) { sx = ax1; sy = ay1; }
    else if (fe == 4) { sx = ax2; sy = ay2; }
    else              { sx = ax3; sy = ay3; }
    r0 += A2[e].x * sx;
    r1 += A2[e].y * sy;
  }
  r0 *= 0.25f; r1 *= 0.25f;

  ((float2*)out)[P * 64 + o2] = make_float2(r0, r1);
}

extern "C" void kernel_launch(void* const* d_in, const int* in_sizes, int n_in,
                              void* d_out, int out_size, void* d_ws, size_t ws_size,
                              hipStream_t stream) {
  const int* archs = (const int*)d_in[0];
  float* ws = (float*)d_ws;
  precompute_kernel<<<8, 512, 0, stream>>>(
      (const float*)d_in[1], (const float*)d_in[2], (const float*)d_in[3],
      (const float*)d_in[4], (const float*)d_in[5], (const float*)d_in[6],
      (const float*)d_in[7], (const float*)d_in[8], (const float*)d_in[9],
      (const float*)d_in[10], (const float*)d_in[11], ws);
  main_kernel<<<NPAIR / 8, 512, 0, stream>>>(archs, (const float*)d_in[9], ws,
                                             (float*)d_out);
}